// Round 3
// baseline (228.754 us; speedup 1.0000x reference)
//
#include <hip/hip_runtime.h>
#include <hip/hip_bf16.h>

#define TOKENS    16384      // B*N = 4*4096
#define DIM       2048
#define NEXP      8
#define NBATCH    4
#define TOK_PER_B 4096
#define ALPHA     0.1f
#define NBLK      512
#define NWAVE     8
#define TPW       4          // tokens per wave

// ws layout: per block 16 floats: [0..7] score sums, [8..15] top-k counts.
// 512 blocks * 16 floats = 32 KiB. Fully overwritten each call (no init needed).

__device__ __forceinline__ float dot4(float4 a, float4 b) {
    return a.x * b.x + a.y * b.y + a.z * b.z + a.w * b.w;
}

__global__ __launch_bounds__(512, 4)
void gate_kernel(const float* __restrict__ x, const float* __restrict__ W,
                 float* __restrict__ out, float* __restrict__ ws)
{
    __shared__ float Wl[NEXP * DIM];          // 64 KiB
    __shared__ float s_part[NWAVE][NEXP];     // per-wave score-sum partials
    __shared__ float s_pcnt[NWAVE][NEXP];     // per-wave count partials

    const int tid = threadIdx.x;

    // Cooperative W load: 4096 float4 across 512 threads -> 8 each.
    {
        const float4* W4  = (const float4*)W;
        float4*       Wl4 = (float4*)Wl;
        #pragma unroll
        for (int i = 0; i < 8; ++i)
            Wl4[tid + i * 512] = W4[tid + i * 512];
    }
    __syncthreads();

    const int wave  = tid >> 6;                    // 0..7
    const int lane  = tid & 63;
    const int gw    = blockIdx.x * NWAVE + wave;   // 0..4095
    const int t0    = gw * TPW;                    // 4 tokens, same batch
    const bool b0   = lane & 1;
    const bool b1   = lane & 2;
    const bool b2   = lane & 4;
    const int  myexp = lane & 7;
    const int  grp8  = (lane >> 3) * 8;

    float pacc = 0.f, cacc = 0.f;

    const float4* xr = (const float4*)(x + (size_t)t0 * DIM);  // row j at xr + j*(DIM/4)

    float acc[TPW][NEXP];
    #pragma unroll
    for (int j = 0; j < TPW; ++j)
        #pragma unroll
        for (int e = 0; e < NEXP; ++e) acc[j][e] = 0.f;

    // Main loop over 8 dim-chunks of 256 floats; one W read feeds 4 tokens.
    float4 xc[TPW];
    #pragma unroll
    for (int j = 0; j < TPW; ++j) xc[j] = xr[j * (DIM / 4) + lane];

    #pragma unroll
    for (int i = 0; i < 8; ++i) {
        float4 xn[TPW];
        if (i < 7) {
            #pragma unroll
            for (int j = 0; j < TPW; ++j)
                xn[j] = xr[j * (DIM / 4) + lane + (i + 1) * 64];
        }
        float4 wv[NEXP];
        #pragma unroll
        for (int e = 0; e < NEXP; ++e)
            wv[e] = ((const float4*)(Wl + e * DIM))[lane + i * 64];  // conflict-free
        #pragma unroll
        for (int e = 0; e < NEXP; ++e)
            #pragma unroll
            for (int j = 0; j < TPW; ++j)
                acc[j][e] += dot4(xc[j], wv[e]);
        if (i < 7) {
            #pragma unroll
            for (int j = 0; j < TPW; ++j) xc[j] = xn[j];
        }
    }

    // Per-token: reduce-scatter (lane l ends with full logit of expert l&7),
    // then distributed softmax + top-2 via ballots.
    #pragma unroll
    for (int j = 0; j < TPW; ++j) {
        // stage xor1: 8 regs -> 4 (keep experts with bit0(e)==bit0(lane))
        float m0 = b0 ? acc[j][1] : acc[j][0], s0 = b0 ? acc[j][0] : acc[j][1];
        float m1 = b0 ? acc[j][3] : acc[j][2], s1 = b0 ? acc[j][2] : acc[j][3];
        float m2_ = b0 ? acc[j][5] : acc[j][4], s2 = b0 ? acc[j][4] : acc[j][5];
        float m3 = b0 ? acc[j][7] : acc[j][6], s3 = b0 ? acc[j][6] : acc[j][7];
        float k0 = m0 + __shfl_xor(s0, 1, 64);
        float k1 = m1 + __shfl_xor(s1, 1, 64);
        float k2 = m2_ + __shfl_xor(s2, 1, 64);
        float k3 = m3 + __shfl_xor(s3, 1, 64);
        // stage xor2: 4 -> 2
        float n0 = b1 ? k1 : k0, q0 = b1 ? k0 : k1;
        float n1 = b1 ? k3 : k2, q1 = b1 ? k2 : k3;
        float h0 = n0 + __shfl_xor(q0, 2, 64);
        float h1 = n1 + __shfl_xor(q1, 2, 64);
        // stage xor4: 2 -> 1
        float nm = b2 ? h1 : h0, nq = b2 ? h0 : h1;
        float r  = nm + __shfl_xor(nq, 4, 64);
        // reduce over lane groups: full 64-lane sum for expert lane&7
        r += __shfl_xor(r, 8, 64);
        r += __shfl_xor(r, 16, 64);
        r += __shfl_xor(r, 32, 64);

        // distributed softmax over the 8 experts (lanes grp..grp+7)
        float m = r;
        m = fmaxf(m, __shfl_xor(m, 1, 64));
        m = fmaxf(m, __shfl_xor(m, 2, 64));
        m = fmaxf(m, __shfl_xor(m, 4, 64));
        float p = __expf(r - m);
        float s = p;
        s += __shfl_xor(s, 1, 64);
        s += __shfl_xor(s, 2, 64);
        s += __shfl_xor(s, 4, 64);
        float inv = 1.0f / s;

        // top-1: value = 1/s, index = lowest lane in group with r==m (jax tie-break)
        unsigned long long bm = __ballot(r == m);
        int i0 = __ffs((unsigned)((bm >> grp8) & 0xffULL)) - 1;
        // top-2: mask i0, repeat
        float rm = (myexp == i0) ? -3.4e38f : r;
        float mm = rm;
        mm = fmaxf(mm, __shfl_xor(mm, 1, 64));
        mm = fmaxf(mm, __shfl_xor(mm, 2, 64));
        mm = fmaxf(mm, __shfl_xor(mm, 4, 64));
        unsigned long long bm2 = __ballot(rm == mm);
        int i1 = __ffs((unsigned)((bm2 >> grp8) & 0xffULL)) - 1;

        float v0 = inv;                     // exp(m-m)/s
        float v1 = __expf(mm - m) * inv;

        pacc += p * inv;                    // this lane's expert score
        cacc += (myexp == i0 ? 1.f : 0.f) + (myexp == i1 ? 1.f : 0.f);

        if (lane == 0) {
            const int t = t0 + j;
            out[(size_t)t * 2 + 0] = v0;
            out[(size_t)t * 2 + 1] = v1;
            out[(size_t)TOKENS * 2 + (size_t)t * 2 + 0] = (float)i0;
            out[(size_t)TOKENS * 2 + (size_t)t * 2 + 1] = (float)i1;
        }
    }

    // Deterministic block reduction: wave partials -> fixed-order sum.
    if (lane < NEXP) {
        s_part[wave][lane] = pacc;   // all 8 lane-groups identical; use group 0
        s_pcnt[wave][lane] = cacc;
    }
    __syncthreads();
    if (tid < NEXP) {
        float sp = 0.f, sc = 0.f;
        #pragma unroll
        for (int w = 0; w < NWAVE; ++w) { sp += s_part[w][tid]; sc += s_pcnt[w][tid]; }
        ws[blockIdx.x * 16 + tid]     = sp;
        ws[blockIdx.x * 16 + 8 + tid] = sc;
    }
}

__global__ void finalize_kernel(const float* __restrict__ ws, float* __restrict__ out)
{
    __shared__ float red[64];
    const int tid = threadIdx.x;
    if (tid < 64) {
        const int b = tid >> 4, c = tid & 15;   // batch, counter
        float acc = 0.f;
        #pragma unroll 4
        for (int k = 0; k < 128; ++k)           // 128 blocks per batch
            acc += ws[(b * 128 + k) * 16 + c];
        red[tid] = acc;
    }
    __syncthreads();
    if (tid == 0) {
        float aux = 0.f;
        for (int b = 0; b < NBATCH; ++b) {
            float a2 = 0.f;
            for (int e = 0; e < NEXP; ++e) {
                float pi = red[b * 16 + e] * (1.f / TOK_PER_B);
                float fi = red[b * 16 + 8 + e] * ((float)NEXP / (2.f * TOK_PER_B));
                a2 += fi * pi;
            }
            aux += a2;
        }
        out[(size_t)TOKENS * 4] = aux * (1.f / NBATCH) * ALPHA;  // out[65536]
    }
}

extern "C" void kernel_launch(void* const* d_in, const int* in_sizes, int n_in,
                              void* d_out, int out_size, void* d_ws, size_t ws_size,
                              hipStream_t stream) {
    const float* x = (const float*)d_in[0];
    const float* W = (const float*)d_in[1];
    float* out = (float*)d_out;
    float* ws  = (float*)d_ws;

    gate_kernel<<<dim3(NBLK), dim3(512), 0, stream>>>(x, W, out, ws);
    finalize_kernel<<<1, 64, 0, stream>>>(ws, out);
}

// Round 4
// 205.638 us; speedup vs baseline: 1.1124x; 1.1124x over previous
//
#include <hip/hip_runtime.h>
#include <hip/hip_bf16.h>

#define TOKENS    16384      // B*N = 4*4096
#define DIM       2048
#define NEXP      8
#define NBATCH    4
#define TOK_PER_B 4096
#define ALPHA     0.1f
#define NBLK      512
#define NWAVE     8
#define TPW       4          // tokens per wave (one pass: 512*8*4 = 16384)

// ws layout: per block 16 floats: [0..7] score sums, [8..15] top-k counts.

__device__ __forceinline__ float dot4(float4 a, float4 b) {
    return a.x * b.x + a.y * b.y + a.z * b.z + a.w * b.w;
}

__global__ __launch_bounds__(512, 4)
void gate_kernel(const float* __restrict__ x, const float* __restrict__ W,
                 float* __restrict__ out, float* __restrict__ ws)
{
    __shared__ float Wl[NEXP * DIM];          // 64 KiB
    __shared__ float s_part[NWAVE][NEXP];
    __shared__ float s_pcnt[NWAVE][NEXP];

    const int tid = threadIdx.x;

    // Cooperative W load: 4096 float4 across 512 threads -> 8 each.
    {
        const float4* W4  = (const float4*)W;
        float4*       Wl4 = (float4*)Wl;
        #pragma unroll
        for (int i = 0; i < 8; ++i)
            Wl4[tid + i * 512] = W4[tid + i * 512];
    }
    __syncthreads();

    const int wave  = tid >> 6;                    // 0..7
    const int lane  = tid & 63;
    const int gw    = blockIdx.x * NWAVE + wave;   // 0..4095
    const int t0    = gw * TPW;                    // 4 tokens, same batch
    const bool b0   = lane & 1;
    const bool b1   = lane & 2;
    const bool b2   = lane & 4;
    const int  myexp = lane & 7;
    const int  grp8  = (lane >> 3) * 8;

    float pacc = 0.f, cacc = 0.f;

    const float4* xr  = (const float4*)(x + (size_t)t0 * DIM);
    const float4* Wl4 = (const float4*)Wl;

    float acc[TPW][NEXP];
    #pragma unroll
    for (int j = 0; j < TPW; ++j)
        #pragma unroll
        for (int e = 0; e < NEXP; ++e) acc[j][e] = 0.f;

    // 8 dim-chunks of 256 floats; one W LDS read feeds 4 tokens.
    // Experts processed in pairs -> only 2 float4 W values live at a time.
    #pragma unroll
    for (int i = 0; i < 8; ++i) {
        float4 xc[TPW];
        #pragma unroll
        for (int j = 0; j < TPW; ++j)
            xc[j] = xr[j * (DIM / 4) + i * 64 + lane];
        #pragma unroll
        for (int e = 0; e < NEXP; e += 2) {
            float4 w0 = Wl4[(e    ) * (DIM / 4) + i * 64 + lane];  // conflict-free
            float4 w1 = Wl4[(e + 1) * (DIM / 4) + i * 64 + lane];
            #pragma unroll
            for (int j = 0; j < TPW; ++j) {
                acc[j][e]     += dot4(xc[j], w0);
                acc[j][e + 1] += dot4(xc[j], w1);
            }
        }
    }

    // Per-token: reduce-scatter (lane l -> full logit of expert l&7),
    // distributed softmax + top-2 via ballots (verified in R3).
    #pragma unroll
    for (int j = 0; j < TPW; ++j) {
        float m0 = b0 ? acc[j][1] : acc[j][0], s0 = b0 ? acc[j][0] : acc[j][1];
        float m1 = b0 ? acc[j][3] : acc[j][2], s1 = b0 ? acc[j][2] : acc[j][3];
        float m2_ = b0 ? acc[j][5] : acc[j][4], s2 = b0 ? acc[j][4] : acc[j][5];
        float m3 = b0 ? acc[j][7] : acc[j][6], s3 = b0 ? acc[j][6] : acc[j][7];
        float k0 = m0 + __shfl_xor(s0, 1, 64);
        float k1 = m1 + __shfl_xor(s1, 1, 64);
        float k2 = m2_ + __shfl_xor(s2, 1, 64);
        float k3 = m3 + __shfl_xor(s3, 1, 64);
        float n0 = b1 ? k1 : k0, q0 = b1 ? k0 : k1;
        float n1 = b1 ? k3 : k2, q1 = b1 ? k2 : k3;
        float h0 = n0 + __shfl_xor(q0, 2, 64);
        float h1 = n1 + __shfl_xor(q1, 2, 64);
        float nm = b2 ? h1 : h0, nq = b2 ? h0 : h1;
        float r  = nm + __shfl_xor(nq, 4, 64);
        r += __shfl_xor(r, 8, 64);
        r += __shfl_xor(r, 16, 64);
        r += __shfl_xor(r, 32, 64);

        float m = r;
        m = fmaxf(m, __shfl_xor(m, 1, 64));
        m = fmaxf(m, __shfl_xor(m, 2, 64));
        m = fmaxf(m, __shfl_xor(m, 4, 64));
        float p = __expf(r - m);
        float s = p;
        s += __shfl_xor(s, 1, 64);
        s += __shfl_xor(s, 2, 64);
        s += __shfl_xor(s, 4, 64);
        float inv = 1.0f / s;

        unsigned long long bm = __ballot(r == m);
        int i0 = __ffs((unsigned)((bm >> grp8) & 0xffULL)) - 1;
        float rm = (myexp == i0) ? -3.4e38f : r;
        float mm = rm;
        mm = fmaxf(mm, __shfl_xor(mm, 1, 64));
        mm = fmaxf(mm, __shfl_xor(mm, 2, 64));
        mm = fmaxf(mm, __shfl_xor(mm, 4, 64));
        unsigned long long bm2 = __ballot(rm == mm);
        int i1 = __ffs((unsigned)((bm2 >> grp8) & 0xffULL)) - 1;

        float v0 = inv;
        float v1 = __expf(mm - m) * inv;

        pacc += p * inv;
        cacc += (myexp == i0 ? 1.f : 0.f) + (myexp == i1 ? 1.f : 0.f);

        if (lane == 0) {
            const int t = t0 + j;
            out[(size_t)t * 2 + 0] = v0;
            out[(size_t)t * 2 + 1] = v1;
            out[(size_t)TOKENS * 2 + (size_t)t * 2 + 0] = (float)i0;
            out[(size_t)TOKENS * 2 + (size_t)t * 2 + 1] = (float)i1;
        }
    }

    // Deterministic block reduction: wave partials -> fixed-order sum.
    if (lane < NEXP) {
        s_part[wave][lane] = pacc;   // lane-groups identical; group 0 used
        s_pcnt[wave][lane] = cacc;
    }
    __syncthreads();
    if (tid < NEXP) {
        float sp = 0.f, sc = 0.f;
        #pragma unroll
        for (int w = 0; w < NWAVE; ++w) { sp += s_part[w][tid]; sc += s_pcnt[w][tid]; }
        ws[blockIdx.x * 16 + tid]     = sp;
        ws[blockIdx.x * 16 + 8 + tid] = sc;
    }
}

__global__ void finalize_kernel(const float* __restrict__ ws, float* __restrict__ out)
{
    __shared__ float red[64];
    const int tid = threadIdx.x;
    if (tid < 64) {
        const int b = tid >> 4, c = tid & 15;
        float acc = 0.f;
        #pragma unroll 4
        for (int k = 0; k < 128; ++k)
            acc += ws[(b * 128 + k) * 16 + c];
        red[tid] = acc;
    }
    __syncthreads();
    if (tid == 0) {
        float aux = 0.f;
        for (int b = 0; b < NBATCH; ++b) {
            float a2 = 0.f;
            for (int e = 0; e < NEXP; ++e) {
                float pi = red[b * 16 + e] * (1.f / TOK_PER_B);
                float fi = red[b * 16 + 8 + e] * ((float)NEXP / (2.f * TOK_PER_B));
                a2 += fi * pi;
            }
            aux += a2;
        }
        out[(size_t)TOKENS * 4] = aux * (1.f / NBATCH) * ALPHA;  // out[65536]
    }
}

extern "C" void kernel_launch(void* const* d_in, const int* in_sizes, int n_in,
                              void* d_out, int out_size, void* d_ws, size_t ws_size,
                              hipStream_t stream) {
    const float* x = (const float*)d_in[0];
    const float* W = (const float*)d_in[1];
    float* out = (float*)d_out;
    float* ws  = (float*)d_ws;

    gate_kernel<<<dim3(NBLK), dim3(512), 0, stream>>>(x, W, out, ws);
    finalize_kernel<<<1, 64, 0, stream>>>(ws, out);
}

// Round 5
// 120.305 us; speedup vs baseline: 1.9014x; 1.7093x over previous
//
#include <hip/hip_runtime.h>
#include <hip/hip_bf16.h>

#define TOKENS    16384      // B*N = 4*4096
#define DIM       2048
#define NEXP      8
#define NBATCH    4
#define TOK_PER_B 4096
#define ALPHA     0.1f
#define NBLK      512
#define NWAVE     8
#define TPW       4          // tokens per wave (one pass: 512*8*4 = 16384)

// ws layout: per block 16 floats: [0..7] score sums, [8..15] top-k counts.

__device__ __forceinline__ float dot4(float4 a, float4 b) {
    return a.x * b.x + a.y * b.y + a.z * b.z + a.w * b.w;
}

// launch_bounds arg2: observed on this toolchain to act like CUDA's
// min-BLOCKS-per-CU (R3/R4: arg=4 forced VGPR=64 = 8 waves/SIMD cap -> spill).
// arg=2 -> cap >=128 VGPRs; LDS (64.5KiB) independently limits to 2 blocks/CU.
__global__ __launch_bounds__(512, 2)
void gate_kernel(const float* __restrict__ x, const float* __restrict__ W,
                 float* __restrict__ out, float* __restrict__ ws)
{
    __shared__ float Wl[NEXP * DIM];          // 64 KiB
    __shared__ float s_part[NWAVE][NEXP];
    __shared__ float s_pcnt[NWAVE][NEXP];

    const int tid = threadIdx.x;

    // Cooperative W load: 4096 float4 across 512 threads -> 8 each.
    {
        const float4* W4  = (const float4*)W;
        float4*       Wl4 = (float4*)Wl;
        #pragma unroll
        for (int i = 0; i < 8; ++i)
            Wl4[tid + i * 512] = W4[tid + i * 512];
    }
    __syncthreads();

    const int wave  = tid >> 6;                    // 0..7
    const int lane  = tid & 63;
    const int gw    = blockIdx.x * NWAVE + wave;   // 0..4095
    const int t0    = gw * TPW;                    // 4 tokens, same batch
    const bool b0   = lane & 1;
    const bool b1   = lane & 2;
    const bool b2   = lane & 4;
    const int  myexp = lane & 7;
    const int  grp8  = (lane >> 3) * 8;

    float pacc = 0.f, cacc = 0.f;

    const float4* xr  = (const float4*)(x + (size_t)t0 * DIM);
    const float4* Wl4 = (const float4*)Wl;

    float acc[TPW][NEXP];
    #pragma unroll
    for (int j = 0; j < TPW; ++j)
        #pragma unroll
        for (int e = 0; e < NEXP; ++e) acc[j][e] = 0.f;

    // 8 dim-chunks of 256 floats; one W LDS read feeds 4 tokens.
    // Experts in pairs -> only 2 float4 W values live at a time.
    #pragma unroll
    for (int i = 0; i < 8; ++i) {
        float4 xc[TPW];
        #pragma unroll
        for (int j = 0; j < TPW; ++j)
            xc[j] = xr[j * (DIM / 4) + i * 64 + lane];
        #pragma unroll
        for (int e = 0; e < NEXP; e += 2) {
            float4 w0 = Wl4[(e    ) * (DIM / 4) + i * 64 + lane];  // conflict-free
            float4 w1 = Wl4[(e + 1) * (DIM / 4) + i * 64 + lane];
            #pragma unroll
            for (int j = 0; j < TPW; ++j) {
                acc[j][e]     += dot4(xc[j], w0);
                acc[j][e + 1] += dot4(xc[j], w1);
            }
        }
    }

    // Per-token: reduce-scatter (lane l -> full logit of expert l&7),
    // distributed softmax + top-2 via ballots (verified R3/R4).
    #pragma unroll
    for (int j = 0; j < TPW; ++j) {
        float m0 = b0 ? acc[j][1] : acc[j][0], s0 = b0 ? acc[j][0] : acc[j][1];
        float m1 = b0 ? acc[j][3] : acc[j][2], s1 = b0 ? acc[j][2] : acc[j][3];
        float m2_ = b0 ? acc[j][5] : acc[j][4], s2 = b0 ? acc[j][4] : acc[j][5];
        float m3 = b0 ? acc[j][7] : acc[j][6], s3 = b0 ? acc[j][6] : acc[j][7];
        float k0 = m0 + __shfl_xor(s0, 1, 64);
        float k1 = m1 + __shfl_xor(s1, 1, 64);
        float k2 = m2_ + __shfl_xor(s2, 1, 64);
        float k3 = m3 + __shfl_xor(s3, 1, 64);
        float n0 = b1 ? k1 : k0, q0 = b1 ? k0 : k1;
        float n1 = b1 ? k3 : k2, q1 = b1 ? k2 : k3;
        float h0 = n0 + __shfl_xor(q0, 2, 64);
        float h1 = n1 + __shfl_xor(q1, 2, 64);
        float nm = b2 ? h1 : h0, nq = b2 ? h0 : h1;
        float r  = nm + __shfl_xor(nq, 4, 64);
        r += __shfl_xor(r, 8, 64);
        r += __shfl_xor(r, 16, 64);
        r += __shfl_xor(r, 32, 64);

        float m = r;
        m = fmaxf(m, __shfl_xor(m, 1, 64));
        m = fmaxf(m, __shfl_xor(m, 2, 64));
        m = fmaxf(m, __shfl_xor(m, 4, 64));
        float p = __expf(r - m);
        float s = p;
        s += __shfl_xor(s, 1, 64);
        s += __shfl_xor(s, 2, 64);
        s += __shfl_xor(s, 4, 64);
        float inv = 1.0f / s;

        unsigned long long bm = __ballot(r == m);
        int i0 = __ffs((unsigned)((bm >> grp8) & 0xffULL)) - 1;
        float rm = (myexp == i0) ? -3.4e38f : r;
        float mm = rm;
        mm = fmaxf(mm, __shfl_xor(mm, 1, 64));
        mm = fmaxf(mm, __shfl_xor(mm, 2, 64));
        mm = fmaxf(mm, __shfl_xor(mm, 4, 64));
        unsigned long long bm2 = __ballot(rm == mm);
        int i1 = __ffs((unsigned)((bm2 >> grp8) & 0xffULL)) - 1;

        float v0 = inv;
        float v1 = __expf(mm - m) * inv;

        pacc += p * inv;
        cacc += (myexp == i0 ? 1.f : 0.f) + (myexp == i1 ? 1.f : 0.f);

        if (lane == 0) {
            const int t = t0 + j;
            out[(size_t)t * 2 + 0] = v0;
            out[(size_t)t * 2 + 1] = v1;
            out[(size_t)TOKENS * 2 + (size_t)t * 2 + 0] = (float)i0;
            out[(size_t)TOKENS * 2 + (size_t)t * 2 + 1] = (float)i1;
        }
    }

    // Deterministic block reduction: wave partials -> fixed-order sum.
    if (lane < NEXP) {
        s_part[wave][lane] = pacc;   // lane-groups identical; group 0 used
        s_pcnt[wave][lane] = cacc;
    }
    __syncthreads();
    if (tid < NEXP) {
        float sp = 0.f, sc = 0.f;
        #pragma unroll
        for (int w = 0; w < NWAVE; ++w) { sp += s_part[w][tid]; sc += s_pcnt[w][tid]; }
        ws[blockIdx.x * 16 + tid]     = sp;
        ws[blockIdx.x * 16 + 8 + tid] = sc;
    }
}

__global__ void finalize_kernel(const float* __restrict__ ws, float* __restrict__ out)
{
    __shared__ float red[64];
    const int tid = threadIdx.x;
    if (tid < 64) {
        const int b = tid >> 4, c = tid & 15;
        float acc = 0.f;
        #pragma unroll 4
        for (int k = 0; k < 128; ++k)
            acc += ws[(b * 128 + k) * 16 + c];
        red[tid] = acc;
    }
    __syncthreads();
    if (tid == 0) {
        float aux = 0.f;
        for (int b = 0; b < NBATCH; ++b) {
            float a2 = 0.f;
            for (int e = 0; e < NEXP; ++e) {
                float pi = red[b * 16 + e] * (1.f / TOK_PER_B);
                float fi = red[b * 16 + 8 + e] * ((float)NEXP / (2.f * TOK_PER_B));
                a2 += fi * pi;
            }
            aux += a2;
        }
        out[(size_t)TOKENS * 4] = aux * (1.f / NBATCH) * ALPHA;  // out[65536]
    }
}

extern "C" void kernel_launch(void* const* d_in, const int* in_sizes, int n_in,
                              void* d_out, int out_size, void* d_ws, size_t ws_size,
                              hipStream_t stream) {
    const float* x = (const float*)d_in[0];
    const float* W = (const float*)d_in[1];
    float* out = (float*)d_out;
    float* ws  = (float*)d_ws;

    gate_kernel<<<dim3(NBLK), dim3(512), 0, stream>>>(x, W, out, ws);
    finalize_kernel<<<1, 64, 0, stream>>>(ws, out);
}

// Round 6
// 49.620 us; speedup vs baseline: 4.6102x; 2.4246x over previous
//
#include <hip/hip_runtime.h>
#include <hip/hip_bf16.h>

#define TOKENS    16384      // B*N = 4*4096
#define DIM       2048
#define NEXP      8
#define NBATCH    4
#define TOK_PER_B 4096
#define ALPHA     0.1f
#define NBLK      512
#define NWAVE     8

// ws layout: per block 16 floats: [0..7] score sums, [8..15] top-k counts.

__device__ __forceinline__ float dot4(float4 a, float4 b) {
    return a.x * b.x + a.y * b.y + a.z * b.z + a.w * b.w;
}

// arg2=2: VGPR cap 128 (R5 measured). Live set kept ~80 by processing tokens
// in 2-token passes and limiting chunk-loop unroll (R5 lesson: full unroll
// hoists all x loads -> 128 regs of x alone -> spill).
__global__ __launch_bounds__(512, 2)
void gate_kernel(const float* __restrict__ x, const float* __restrict__ W,
                 float* __restrict__ out, float* __restrict__ ws)
{
    __shared__ float Wl[NEXP * DIM];          // 64 KiB
    __shared__ float s_part[NWAVE][NEXP];
    __shared__ float s_pcnt[NWAVE][NEXP];

    const int tid = threadIdx.x;

    // Cooperative W load: 4096 float4 across 512 threads -> 8 each.
    {
        const float4* W4  = (const float4*)W;
        float4*       Wl4 = (float4*)Wl;
        #pragma unroll
        for (int i = 0; i < 8; ++i)
            Wl4[tid + i * 512] = W4[tid + i * 512];
    }
    __syncthreads();

    const int wave  = tid >> 6;                    // 0..7
    const int lane  = tid & 63;
    const int gw    = blockIdx.x * NWAVE + wave;   // 0..4095
    const int t0    = gw * 4;                      // 4 tokens, same batch
    const bool b0   = lane & 1;
    const bool b1   = lane & 2;
    const bool b2   = lane & 4;
    const int  myexp = lane & 7;
    const int  grp8  = (lane >> 3) * 8;

    float pacc = 0.f, cacc = 0.f;
    const float4* Wl4 = (const float4*)Wl;

    // Two passes of two tokens each: bounds register pressure to the pass.
    #pragma unroll 1
    for (int it = 0; it < 2; ++it) {
        const float4* xr0 = (const float4*)(x + (size_t)(t0 + it * 2) * DIM);
        const float4* xr1 = xr0 + DIM / 4;

        float acc[2][NEXP];
        #pragma unroll
        for (int e = 0; e < NEXP; ++e) { acc[0][e] = 0.f; acc[1][e] = 0.f; }

        // 8 dim-chunks of 256 floats; unroll 2 keeps only ~2 chunks of x live.
        #pragma unroll 2
        for (int i = 0; i < 8; ++i) {
            float4 x0 = xr0[i * 64 + lane];        // coalesced 1 KiB/instr
            float4 x1 = xr1[i * 64 + lane];
            #pragma unroll
            for (int e = 0; e < NEXP; e += 2) {
                float4 w0 = Wl4[(e    ) * (DIM / 4) + i * 64 + lane];  // conflict-free
                float4 w1 = Wl4[(e + 1) * (DIM / 4) + i * 64 + lane];
                acc[0][e]     += dot4(x0, w0);
                acc[1][e]     += dot4(x1, w0);
                acc[0][e + 1] += dot4(x0, w1);
                acc[1][e + 1] += dot4(x1, w1);
            }
        }

        // Per-token: reduce-scatter (lane l -> full logit of expert l&7),
        // distributed softmax + top-2 via ballots (verified R3-R5).
        #pragma unroll
        for (int tk = 0; tk < 2; ++tk) {
            float m0 = b0 ? acc[tk][1] : acc[tk][0], s0 = b0 ? acc[tk][0] : acc[tk][1];
            float m1 = b0 ? acc[tk][3] : acc[tk][2], s1 = b0 ? acc[tk][2] : acc[tk][3];
            float m2_ = b0 ? acc[tk][5] : acc[tk][4], s2 = b0 ? acc[tk][4] : acc[tk][5];
            float m3 = b0 ? acc[tk][7] : acc[tk][6], s3 = b0 ? acc[tk][6] : acc[tk][7];
            float k0 = m0 + __shfl_xor(s0, 1, 64);
            float k1 = m1 + __shfl_xor(s1, 1, 64);
            float k2 = m2_ + __shfl_xor(s2, 1, 64);
            float k3 = m3 + __shfl_xor(s3, 1, 64);
            float n0 = b1 ? k1 : k0, q0 = b1 ? k0 : k1;
            float n1 = b1 ? k3 : k2, q1 = b1 ? k2 : k3;
            float h0 = n0 + __shfl_xor(q0, 2, 64);
            float h1 = n1 + __shfl_xor(q1, 2, 64);
            float nm = b2 ? h1 : h0, nq = b2 ? h0 : h1;
            float r  = nm + __shfl_xor(nq, 4, 64);
            r += __shfl_xor(r, 8, 64);
            r += __shfl_xor(r, 16, 64);
            r += __shfl_xor(r, 32, 64);

            float m = r;
            m = fmaxf(m, __shfl_xor(m, 1, 64));
            m = fmaxf(m, __shfl_xor(m, 2, 64));
            m = fmaxf(m, __shfl_xor(m, 4, 64));
            float p = __expf(r - m);
            float s = p;
            s += __shfl_xor(s, 1, 64);
            s += __shfl_xor(s, 2, 64);
            s += __shfl_xor(s, 4, 64);
            float inv = 1.0f / s;

            unsigned long long bm = __ballot(r == m);
            int i0 = __ffs((unsigned)((bm >> grp8) & 0xffULL)) - 1;
            float rm = (myexp == i0) ? -3.4e38f : r;
            float mm = rm;
            mm = fmaxf(mm, __shfl_xor(mm, 1, 64));
            mm = fmaxf(mm, __shfl_xor(mm, 2, 64));
            mm = fmaxf(mm, __shfl_xor(mm, 4, 64));
            unsigned long long bm2 = __ballot(rm == mm);
            int i1 = __ffs((unsigned)((bm2 >> grp8) & 0xffULL)) - 1;

            float v0 = inv;
            float v1 = __expf(mm - m) * inv;

            pacc += p * inv;
            cacc += (myexp == i0 ? 1.f : 0.f) + (myexp == i1 ? 1.f : 0.f);

            if (lane == 0) {
                const int t = t0 + it * 2 + tk;
                out[(size_t)t * 2 + 0] = v0;
                out[(size_t)t * 2 + 1] = v1;
                out[(size_t)TOKENS * 2 + (size_t)t * 2 + 0] = (float)i0;
                out[(size_t)TOKENS * 2 + (size_t)t * 2 + 1] = (float)i1;
            }
        }
    }

    // Deterministic block reduction: wave partials -> fixed-order sum.
    if (lane < NEXP) {
        s_part[wave][lane] = pacc;   // lane-groups identical; group 0 used
        s_pcnt[wave][lane] = cacc;
    }
    __syncthreads();
    if (tid < NEXP) {
        float sp = 0.f, sc = 0.f;
        #pragma unroll
        for (int w = 0; w < NWAVE; ++w) { sp += s_part[w][tid]; sc += s_pcnt[w][tid]; }
        ws[blockIdx.x * 16 + tid]     = sp;
        ws[blockIdx.x * 16 + 8 + tid] = sc;
    }
}

__global__ void finalize_kernel(const float* __restrict__ ws, float* __restrict__ out)
{
    __shared__ float red[64];
    const int tid = threadIdx.x;
    if (tid < 64) {
        const int b = tid >> 4, c = tid & 15;
        float acc = 0.f;
        #pragma unroll 4
        for (int k = 0; k < 128; ++k)
            acc += ws[(b * 128 + k) * 16 + c];
        red[tid] = acc;
    }
    __syncthreads();
    if (tid == 0) {
        float aux = 0.f;
        for (int b = 0; b < NBATCH; ++b) {
            float a2 = 0.f;
            for (int e = 0; e < NEXP; ++e) {
                float pi = red[b * 16 + e] * (1.f / TOK_PER_B);
                float fi = red[b * 16 + 8 + e] * ((float)NEXP / (2.f * TOK_PER_B));
                a2 += fi * pi;
            }
            aux += a2;
        }
        out[(size_t)TOKENS * 4] = aux * (1.f / NBATCH) * ALPHA;  // out[65536]
    }
}

extern "C" void kernel_launch(void* const* d_in, const int* in_sizes, int n_in,
                              void* d_out, int out_size, void* d_ws, size_t ws_size,
                              hipStream_t stream) {
    const float* x = (const float*)d_in[0];
    const float* W = (const float*)d_in[1];
    float* out = (float*)d_out;
    float* ws  = (float*)d_ws;

    gate_kernel<<<dim3(NBLK), dim3(512), 0, stream>>>(x, W, out, ws);
    finalize_kernel<<<1, 64, 0, stream>>>(ws, out);
}